// Round 3
// baseline (729.573 us; speedup 1.0000x reference)
//
#include <hip/hip_runtime.h>

#define BB 256
#define TT 1024
#define HH 128
#define CC 2

__global__ __launch_bounds__(256, 1) void rnn_kernel(
    const float* __restrict__ x, const float* __restrict__ W_ih,
    const float* __restrict__ W_hh, const float* __restrict__ b_ih,
    const float* __restrict__ b_hh, const float* __restrict__ W_fc,
    const float* __restrict__ b_fc, float* __restrict__ out)
{
    const int b    = blockIdx.x;
    const int tid  = threadIdx.x;
    const int lane = tid & 63;
    const int wv   = tid >> 6;                  // 0..3
    const int row  = (wv << 5) + (lane >> 1);   // 0..127, lane pair = one row
    const int ks   = lane & 1;                  // K-half of the dot; also = class for logits

    __shared__ float xs[TT];          // input sequence for this batch row
    __shared__ float hbuf[2][HH];     // double-buffered hidden state
    __shared__ float qpart[2][4][2];  // per-wave logit partials, double-buffered

    // preload x row (coalesced float4)
    {
        const float4* xr = (const float4*)(x + (size_t)b * TT);
        ((float4*)xs)[tid] = xr[tid];
    }
    if (tid < HH) hbuf[0][tid] = 0.f;

    // per-thread constants
    const float wih  = W_ih[row];               // INPUT_DIM = 1
    const float bias = b_ih[row] + b_hh[row];
    const float wfcr = W_fc[ks * HH + row];     // this lane's class = ks
    const float bfc  = (tid < CC) ? b_fc[tid] : 0.f;

    // W_hh K-half of this row in registers (64 VGPRs)
    float4 wr[16];
    {
        const float4* wrow = (const float4*)(W_hh + row * HH + ks * 64);
        #pragma unroll
        for (int j = 0; j < 16; ++j) wr[j] = wrow[j];
    }

    __syncthreads();

    float* o = out + (size_t)b * TT * CC;

#define STEP(CUR, NXT, T)                                                      \
    {                                                                          \
        const int t = (T);                                                     \
        /* store logits of step t-1 (qpart written last iter, other buffer) */ \
        if (t > 0 && tid < CC) {                                               \
            const int pb = (t ^ 1) & 1;                                        \
            o[(t - 1) * CC + tid] = qpart[pb][0][tid] + qpart[pb][1][tid]      \
                                  + qpart[pb][2][tid] + qpart[pb][3][tid] + bfc;\
        }                                                                      \
        /* matvec: each lane does its K-half, broadcast LDS reads (free) */    \
        const float4* hb = (const float4*)(hbuf[CUR] + (ks << 6));             \
        float a0 = 0.f, a1 = 0.f, a2 = 0.f, a3 = 0.f;                          \
        _Pragma("unroll")                                                      \
        for (int j = 0; j < 16; ++j) {                                         \
            float4 v = hb[j];                                                  \
            a0 = fmaf(wr[j].x, v.x, a0);                                       \
            a1 = fmaf(wr[j].y, v.y, a1);                                       \
            a2 = fmaf(wr[j].z, v.z, a2);                                       \
            a3 = fmaf(wr[j].w, v.w, a3);                                       \
        }                                                                      \
        float p = (a0 + a1) + (a2 + a3);                                       \
        p += __shfl_xor(p, 1);               /* combine K-halves in-wave */    \
        float u  = fmaf(xs[t], wih, bias) + p;                                 \
        float hn = tanhf(u);                 /* both pair lanes compute it */  \
        if (ks == 0) hbuf[NXT][row] = hn;    /* conflict-free write */         \
        /* logits for step t from registers; parity-preserving xor-tree */     \
        float q = hn * wfcr;                                                   \
        q += __shfl_xor(q, 2);                                                 \
        q += __shfl_xor(q, 4);                                                 \
        q += __shfl_xor(q, 8);                                                 \
        q += __shfl_xor(q, 16);                                                \
        q += __shfl_xor(q, 32);                                                \
        if (lane < CC) qpart[t & 1][wv][lane] = q;                             \
        __syncthreads();                     /* the single per-step barrier */ \
    }

    for (int tt = 0; tt < TT; tt += 2) {
        STEP(0, 1, tt);
        STEP(1, 0, tt + 1);
    }

    // final step's logits
    if (tid < CC) {
        const int pb = (TT - 1) & 1;
        o[(TT - 1) * CC + tid] = qpart[pb][0][tid] + qpart[pb][1][tid]
                               + qpart[pb][2][tid] + qpart[pb][3][tid] + bfc;
    }
#undef STEP
}

extern "C" void kernel_launch(void* const* d_in, const int* in_sizes, int n_in,
                              void* d_out, int out_size, void* d_ws, size_t ws_size,
                              hipStream_t stream) {
    const float* x    = (const float*)d_in[0];
    const float* W_ih = (const float*)d_in[1];
    const float* W_hh = (const float*)d_in[2];
    const float* b_ih = (const float*)d_in[3];
    const float* b_hh = (const float*)d_in[4];
    const float* W_fc = (const float*)d_in[5];
    const float* b_fc = (const float*)d_in[6];
    float* out = (float*)d_out;

    rnn_kernel<<<BB, 256, 0, stream>>>(x, W_ih, W_hh, b_ih, b_hh, W_fc, b_fc, out);
}